// Round 14
// baseline (81.790 us; speedup 1.0000x reference)
//
#include <hip/hip_runtime.h>
#include <hip/hip_bf16.h>

#define HH 512
#define BB 8192
#define KK 1536
#define NT 48              // K tiles of 32
#define HB 4194304         // 512*8192
#define BLOB 8192          // bhalf per 16KB blob

typedef __bf16 bhalf;
typedef __bf16 bf16x8 __attribute__((ext_vector_type(8)));
typedef float  f32x4  __attribute__((ext_vector_type(4)));

typedef __attribute__((address_space(1))) void* as1_t;
typedef __attribute__((address_space(3))) void* as3_t;

#define GLDS(src, dst) __builtin_amdgcn_global_load_lds((as1_t)(void*)(src), (as3_t)(void*)(dst), 16, 0, 0)
#define SBAR() asm volatile("s_barrier" ::: "memory")
#define VM0()  asm volatile("s_waitcnt vmcnt(0)" ::: "memory")

// Packed blob layout (k-major, conflict-free): blob = one (256-row, 32-k)
// tile = 16 KB.  slot s = rb*64 + hi*16 + lr.  Element (row rb*16+lr,
// k hi*8+e) at bhalf offset s*8+e.  Zero bank conflicts (verified R4).
// Rows 0..127 occupy the first 8 KB -> a BN=128 block stages a half-blob.

// ---------------------------------------------------------------------------
// prep_all: blocks 0..1535 = prep_x (+ z_hat partials); 1536..2047 = prep_w.
// ---------------------------------------------------------------------------
__global__ __launch_bounds__(256) void prep_all(
    const float* __restrict__ h, const float* __restrict__ ht,
    const float* __restrict__ hb, const float* __restrict__ z,
    const float* __restrict__ zb, const float* __restrict__ U11,
    const float* __restrict__ U21, const float* __restrict__ W01,
    bhalf* __restrict__ XtP, bhalf* __restrict__ WcP,
    float* __restrict__ zpart)
{
    const int tid = threadIdx.x;
    const int b   = blockIdx.x;

    if (b < 1536) {
        // ---------------- prep_x ----------------
        __shared__ float tile[32][257];
        const int kt = b % 48;           // 0..47
        const int nt = b / 48;           // 0..31
        const int n  = nt * 256 + tid;
        const int kb = kt * 32;

        const float* src; const float* wsrc; int kr; float scale;
        if (kb < 512)       { src = h;  wsrc = U11 + (size_t)2048 * 512 + kb;
                              kr = kb;        scale = 1.f - z[n]; }
        else if (kb < 1024) { src = ht; wsrc = U21 + (size_t)2048 * 512 + (kb - 512);
                              kr = kb - 512;  scale = z[n]; }
        else                { src = hb; wsrc = W01 + (size_t)2048 * 512 + (kb - 1024);
                              kr = kb - 1024; scale = zb[n]; }

        float zp = 0.f;
        #pragma unroll
        for (int kk = 0; kk < 32; ++kk) {
            const float v = src[(size_t)(kr + kk) * BB + n] * scale;
            tile[kk][tid] = v;
            zp += v * wsrc[kk];          // uniform w -> scalar loads
        }
        zpart[(size_t)kt * BB + n] = zp;
        __syncthreads();

        bhalf* blob = XtP + (size_t)(nt * NT + kt) * BLOB;
        #pragma unroll
        for (int q = 0; q < 4; ++q) {
            const int s  = q * 256 + tid;
            const int rb = s >> 6, w = s & 63;
            const int hh = w >> 4, lrr = w & 15;  // slot = rb*64 + hh*16 + lrr
            const int nloc = rb * 16 + lrr, kloc = hh * 8;
            bf16x8 r;
            #pragma unroll
            for (int e = 0; e < 8; ++e) r[e] = (bhalf)tile[kloc + e][nloc];
            *(bf16x8*)(blob + s * 8) = r;
        }
    } else {
        // ---------------- prep_w ----------------
        const int o    = (b - 1536) * 4 + (tid >> 6);   // 0..2047
        const int lane = tid & 63;
        const int g = o >> 9, j = o & 511;
        const int mp = 4 * j + g;
        const int mt = mp >> 8, rb = (mp >> 4) & 15, lrr = mp & 15;

        #pragma unroll
        for (int p = 0; p < 3; ++p) {
            const float* src = (p == 0) ? U11 : (p == 1) ? U21 : W01;
            const float* rp  = src + (size_t)o * 512 + lane * 8;
            float4 v0 = *(const float4*)rp;
            float4 v1 = *(const float4*)(rp + 4);
            bf16x8 r;
            r[0]=(bhalf)v0.x; r[1]=(bhalf)v0.y; r[2]=(bhalf)v0.z; r[3]=(bhalf)v0.w;
            r[4]=(bhalf)v1.x; r[5]=(bhalf)v1.y; r[6]=(bhalf)v1.z; r[7]=(bhalf)v1.w;
            const int kt = p * 16 + (lane >> 2);
            const int hh = lane & 3;
            *(bf16x8*)(WcP + (size_t)(mt * NT + kt) * BLOB
                       + rb * 512 + hh * 128 + lrr * 8) = r;
        }
    }
}

// ---------------------------------------------------------------------------
__device__ __forceinline__ float sigmf(float x)    { return 1.f / (1.f + __expf(-x)); }
__device__ __forceinline__ float tanhfast(float x) { return 2.f / (1.f + __expf(-2.f * x)) - 1.f; }

// ---------------------------------------------------------------------------
// gemm_fused: R9 structure verbatim (best measured 63.5 us): BM=256 x BN=128,
// 512 threads = 8 waves (4M x 2N, wave tile 64x64), BK=32, 2 LDS buffers
// (48 KB) -> 2 blocks/CU, 4 waves/SIMD.  One vmcnt(0)+barrier per K-tile;
// STAGE(t+1) under CT(t).  Fused gate epilogue with non-temporal c/h/out
// (read/write-once; keep L2 for operand panels).
// z_hat finalize: mt==0 blocks sum the 48 prep-computed partials per column
// at kernel start (hidden under prologue staging).
// ---------------------------------------------------------------------------
__global__ __launch_bounds__(512, 4) void gemm_fused(
    const bhalf* __restrict__ WcP, const bhalf* __restrict__ XtP,
    const float* __restrict__ bias, const float* __restrict__ c_in,
    const float* __restrict__ h_in, const float* __restrict__ z,
    const float* __restrict__ zb, const float* __restrict__ zpart,
    float* __restrict__ out)
{
    __shared__ bhalf As[2][BLOB];        // 2 x 16 KB (A: 256 rows x 32 k)
    __shared__ bhalf Bs[2][BLOB / 2];    // 2 x  8 KB (B: 128 rows x 32 k)

    const int tid  = threadIdx.x;
    const int lane = tid & 63;
    const int wid  = tid >> 6;          // 0..7
    const int wm   = wid >> 1, wn = wid & 1;   // 4M x 2N
    const int lr   = lane & 15, hi = lane >> 4;
    const int soff = hi * 128 + lr * 8;      // k-major fragment offset (bhalf)

    const int xcd = blockIdx.x & 7;
    const int i   = blockIdx.x >> 3;                 // 0..63
    const int mt  = ((xcd & 3) << 1) | (i & 1);      // 0..7
    const int nt2 = ((xcd >> 2) << 5) | (i >> 1);    // 0..63 (128-col panels)
    const int n0 = nt2 * 128;
    const int jb = mt * 64;

    const bhalf* gA = WcP + (size_t)mt * (NT * BLOB) + tid * 8;
    const bhalf* gB = XtP + (size_t)(nt2 >> 1) * (NT * BLOB)
                          + (nt2 & 1) * (BLOB / 2) + tid * 8;

    // wave tile 64x64: A rows wm*64.. (4 rb-blocks = 2048 bhalf), B rows wn*64
    const bhalf* pA0 = &As[0][wm * 2048 + soff];
    const bhalf* pA1 = &As[1][wm * 2048 + soff];
    const bhalf* pB0 = &Bs[0][wn * 2048 + soff];
    const bhalf* pB1 = &Bs[1][wn * 2048 + soff];

// 3 gload_lds per tile: A 16 KB (2 x 8KB), B 8 KB (1)
#define STAGE(t, bf) do {                                                     \
        const bhalf* sa_ = gA + (size_t)(t) * BLOB;                           \
        const bhalf* sb_ = gB + (size_t)(t) * BLOB;                           \
        GLDS(sa_,        &As[bf][tid * 8]);                                   \
        GLDS(sa_ + 4096, &As[bf][tid * 8 + 4096]);                            \
        GLDS(sb_,        &Bs[bf][tid * 8]);                                   \
    } while (0)

#define MF(mi, ni, A_, B_) acc[mi][ni] = \
    __builtin_amdgcn_mfma_f32_16x16x32_bf16(A_, B_, acc[mi][ni], 0, 0, 0)

// one K-32 tile from buffer q: 8 ds_read_b128 + 16 MFMA, compiler-scheduled
#define CT(q) do {                                                            \
    bf16x8 b0 = *(const bf16x8*)(pB##q);                                      \
    bf16x8 b1 = *(const bf16x8*)(pB##q + 512);                                \
    bf16x8 b2 = *(const bf16x8*)(pB##q + 1024);                               \
    bf16x8 b3 = *(const bf16x8*)(pB##q + 1536);                               \
    bf16x8 a0 = *(const bf16x8*)(pA##q);                                      \
    bf16x8 a1 = *(const bf16x8*)(pA##q + 512);                                \
    bf16x8 a2 = *(const bf16x8*)(pA##q + 1024);                               \
    bf16x8 a3 = *(const bf16x8*)(pA##q + 1536);                               \
    __builtin_amdgcn_s_setprio(1);                                            \
    MF(0,0,a0,b0); MF(0,1,a0,b1); MF(0,2,a0,b2); MF(0,3,a0,b3);               \
    MF(1,0,a1,b0); MF(1,1,a1,b1); MF(1,2,a1,b2); MF(1,3,a1,b3);               \
    MF(2,0,a2,b0); MF(2,1,a2,b1); MF(2,2,a2,b2); MF(2,3,a2,b3);               \
    MF(3,0,a3,b0); MF(3,1,a3,b1); MF(3,2,a3,b2); MF(3,3,a3,b3);               \
    __builtin_amdgcn_s_setprio(0);                                            \
} while (0)

    f32x4 acc[4][4] = {};

    // prologue
    STAGE(0, 0);

    // ---- z_hat finalize (hidden under prologue): mt==0, 128 cols/block ----
    if (mt == 0 && tid < 128) {
        const int n = n0 + tid;
        float s = 0.f;
        #pragma unroll
        for (int kt2 = 0; kt2 < NT; ++kt2)
            s += __builtin_nontemporal_load(zpart + (size_t)kt2 * BB + n);
        const float v = (s + bias[2048] + 1.f) * 0.5f;
        __builtin_nontemporal_store(fminf(fmaxf(v, 0.f), 1.f),
                                    out + (size_t)2 * HB + n);
    }

    // steady state: at top of tile t only tile t's 3 loads are outstanding;
    // VM0 drains them (they had all of CT(t-1) to land); one barrier/tile;
    // STAGE(t+1) issues before CT(t) so it overlaps the compute.
    for (int t = 0; t < 46; t += 2) {
        VM0(); SBAR(); STAGE(t + 1, 1); CT(0);
        VM0(); SBAR(); STAGE(t + 2, 0); CT(1);
    }
    VM0(); SBAR(); STAGE(47, 1); CT(0);      // t=46
    VM0(); SBAR(); CT(1);                    // t=47

    // ---- fused gate epilogue: acc[mi][ni][r] = gate r of hidden j ----
    const int colbase = n0 + wn * 64 + lr;
    const int jloc0   = wm * 16 + hi;
    float zc[4], zbc[4];
    #pragma unroll
    for (int ni = 0; ni < 4; ++ni) {
        zc[ni]  = z[colbase + ni * 16];
        zbc[ni] = zb[colbase + ni * 16];
    }
    #pragma unroll
    for (int mi = 0; mi < 4; ++mi) {
        const int j = jb + jloc0 + mi * 4;           // hidden index
        const float bf_ = bias[j];
        const float bi_ = bias[512 + j];
        const float bo_ = bias[1024 + j];
        const float bg_ = bias[1536 + j];
        #pragma unroll
        for (int ni = 0; ni < 4; ++ni) {
            const int col = colbase + ni * 16;
            const size_t idx = (size_t)j * BB + col;
            const float cv = __builtin_nontemporal_load(c_in + idx);
            const float hv = __builtin_nontemporal_load(h_in + idx);
            const float fv = sigmf(acc[mi][ni][0] + bf_);
            const float iv = sigmf(acc[mi][ni][1] + bi_);
            const float ov = sigmf(acc[mi][ni][2] + bo_);
            const float gv = tanhfast(acc[mi][ni][3] + bg_);
            const float ig = iv * gv;
            const float zq = zc[ni], zbq = zbc[ni];
            const float cn = zq * ig + (1.f - zq) * (1.f - zbq) * cv
                           + (1.f - zq) * zbq * (fv * cv + ig);
            const float tc = tanhfast(cn);
            const float hn = (zq + (1.f - zq) * zbq) * ov * tc
                           + (1.f - zq) * (1.f - zbq) * hv;
            __builtin_nontemporal_store(hn, out + idx);
            __builtin_nontemporal_store(cn, out + HB + idx);
        }
    }
}

// ---------------------------------------------------------------------------
extern "C" void kernel_launch(void* const* d_in, const int* in_sizes, int n_in,
                              void* d_out, int out_size, void* d_ws, size_t ws_size,
                              hipStream_t stream) {
    const float* c    = (const float*)d_in[0];
    const float* hb   = (const float*)d_in[1];
    const float* h    = (const float*)d_in[2];
    const float* ht   = (const float*)d_in[3];
    const float* z    = (const float*)d_in[4];
    const float* zb   = (const float*)d_in[5];
    const float* U11  = (const float*)d_in[6];
    const float* U21  = (const float*)d_in[7];
    const float* W01  = (const float*)d_in[8];
    const float* bias = (const float*)d_in[9];
    float* out = (float*)d_out;

    char* ws = (char*)d_ws;
    bhalf* XtP   = (bhalf*)ws;                     // 32*48*16KB = 25165824 B
    bhalf* WcP   = (bhalf*)(ws + 25165824);        //  8*48*16KB =  6291456 B
    float* zpart = (float*)(ws + 25165824 + 6291456);  // 48*8192*4 = 1572864 B

    prep_all  <<<2048, 256, 0, stream>>>(h, ht, hb, z, zb, U11, U21, W01,
                                         XtP, WcP, zpart);
    gemm_fused<<<512, 512, 0, stream>>>(WcP, XtP, bias, c, h, z, zb,
                                        zpart, out);
}

// Round 15
// 74.226 us; speedup vs baseline: 1.1019x; 1.1019x over previous
//
#include <hip/hip_runtime.h>
#include <hip/hip_bf16.h>

#define HH 512
#define BB 8192
#define KK 1536
#define NT 48              // K tiles of 32
#define HB 4194304         // 512*8192
#define BLOB 8192          // bhalf per 16KB blob

typedef __bf16 bhalf;
typedef __bf16 bf16x8 __attribute__((ext_vector_type(8)));
typedef float  f32x4  __attribute__((ext_vector_type(4)));

typedef __attribute__((address_space(1))) void* as1_t;
typedef __attribute__((address_space(3))) void* as3_t;

#define GLDS(src, dst) __builtin_amdgcn_global_load_lds((as1_t)(void*)(src), (as3_t)(void*)(dst), 16, 0, 0)
#define SBAR() asm volatile("s_barrier" ::: "memory")
#define VM0()  asm volatile("s_waitcnt vmcnt(0)" ::: "memory")

// Packed blob layout (k-major, conflict-free): blob = one (256-row, 32-k)
// tile = 16 KB.  slot s = rb*64 + hi*16 + lr.  Element (row rb*16+lr,
// k hi*8+e) at bhalf offset s*8+e.  Zero bank conflicts (verified R4).
// Rows 0..127 occupy the first 8 KB -> a BN=128 block stages a half-blob.

// ---------------------------------------------------------------------------
// prep_all: blocks 0..1535 = prep_x (+ z_hat partials); 1536..2047 = prep_w.
// ---------------------------------------------------------------------------
__global__ __launch_bounds__(256) void prep_all(
    const float* __restrict__ h, const float* __restrict__ ht,
    const float* __restrict__ hb, const float* __restrict__ z,
    const float* __restrict__ zb, const float* __restrict__ U11,
    const float* __restrict__ U21, const float* __restrict__ W01,
    bhalf* __restrict__ XtP, bhalf* __restrict__ WcP,
    float* __restrict__ zpart)
{
    const int tid = threadIdx.x;
    const int b   = blockIdx.x;

    if (b < 1536) {
        // ---------------- prep_x ----------------
        __shared__ float tile[32][257];
        const int kt = b % 48;           // 0..47
        const int nt = b / 48;           // 0..31
        const int n  = nt * 256 + tid;
        const int kb = kt * 32;

        const float* src; const float* wsrc; int kr; float scale;
        if (kb < 512)       { src = h;  wsrc = U11 + (size_t)2048 * 512 + kb;
                              kr = kb;        scale = 1.f - z[n]; }
        else if (kb < 1024) { src = ht; wsrc = U21 + (size_t)2048 * 512 + (kb - 512);
                              kr = kb - 512;  scale = z[n]; }
        else                { src = hb; wsrc = W01 + (size_t)2048 * 512 + (kb - 1024);
                              kr = kb - 1024; scale = zb[n]; }

        float zp = 0.f;
        #pragma unroll
        for (int kk = 0; kk < 32; ++kk) {
            const float v = src[(size_t)(kr + kk) * BB + n] * scale;
            tile[kk][tid] = v;
            zp += v * wsrc[kk];          // uniform w -> scalar loads
        }
        zpart[(size_t)kt * BB + n] = zp;
        __syncthreads();

        bhalf* blob = XtP + (size_t)(nt * NT + kt) * BLOB;
        #pragma unroll
        for (int q = 0; q < 4; ++q) {
            const int s  = q * 256 + tid;
            const int rb = s >> 6, w = s & 63;
            const int hh = w >> 4, lrr = w & 15;  // slot = rb*64 + hh*16 + lrr
            const int nloc = rb * 16 + lrr, kloc = hh * 8;
            bf16x8 r;
            #pragma unroll
            for (int e = 0; e < 8; ++e) r[e] = (bhalf)tile[kloc + e][nloc];
            *(bf16x8*)(blob + s * 8) = r;
        }
    } else {
        // ---------------- prep_w ----------------
        const int o    = (b - 1536) * 4 + (tid >> 6);   // 0..2047
        const int lane = tid & 63;
        const int g = o >> 9, j = o & 511;
        const int mp = 4 * j + g;
        const int mt = mp >> 8, rb = (mp >> 4) & 15, lrr = mp & 15;

        #pragma unroll
        for (int p = 0; p < 3; ++p) {
            const float* src = (p == 0) ? U11 : (p == 1) ? U21 : W01;
            const float* rp  = src + (size_t)o * 512 + lane * 8;
            float4 v0 = *(const float4*)rp;
            float4 v1 = *(const float4*)(rp + 4);
            bf16x8 r;
            r[0]=(bhalf)v0.x; r[1]=(bhalf)v0.y; r[2]=(bhalf)v0.z; r[3]=(bhalf)v0.w;
            r[4]=(bhalf)v1.x; r[5]=(bhalf)v1.y; r[6]=(bhalf)v1.z; r[7]=(bhalf)v1.w;
            const int kt = p * 16 + (lane >> 2);
            const int hh = lane & 3;
            *(bf16x8*)(WcP + (size_t)(mt * NT + kt) * BLOB
                       + rb * 512 + hh * 128 + lrr * 8) = r;
        }
    }
}

// ---------------------------------------------------------------------------
__device__ __forceinline__ float sigmf(float x)    { return 1.f / (1.f + __expf(-x)); }
__device__ __forceinline__ float tanhfast(float x) { return 2.f / (1.f + __expf(-2.f * x)) - 1.f; }

// ---------------------------------------------------------------------------
// gemm_fused: R9 structure verbatim (best measured 63.5 us): BM=256 x BN=128,
// 512 threads = 8 waves (4M x 2N, wave tile 64x64), BK=32, 2 LDS buffers
// (48 KB) -> 2 blocks/CU, 4 waves/SIMD.  One vmcnt(0)+barrier per K-tile;
// STAGE(t+1) under CT(t).  Fused gate epilogue.
// z_hat finalize: mt==0 blocks sum the 48 prep-computed partials per column
// at kernel start (hidden under prologue staging).
// ---------------------------------------------------------------------------
__global__ __launch_bounds__(512, 4) void gemm_fused(
    const bhalf* __restrict__ WcP, const bhalf* __restrict__ XtP,
    const float* __restrict__ bias, const float* __restrict__ c_in,
    const float* __restrict__ h_in, const float* __restrict__ z,
    const float* __restrict__ zb, const float* __restrict__ zpart,
    float* __restrict__ out)
{
    __shared__ bhalf As[2][BLOB];        // 2 x 16 KB (A: 256 rows x 32 k)
    __shared__ bhalf Bs[2][BLOB / 2];    // 2 x  8 KB (B: 128 rows x 32 k)

    const int tid  = threadIdx.x;
    const int lane = tid & 63;
    const int wid  = tid >> 6;          // 0..7
    const int wm   = wid >> 1, wn = wid & 1;   // 4M x 2N
    const int lr   = lane & 15, hi = lane >> 4;
    const int soff = hi * 128 + lr * 8;      // k-major fragment offset (bhalf)

    const int xcd = blockIdx.x & 7;
    const int i   = blockIdx.x >> 3;                 // 0..63
    const int mt  = ((xcd & 3) << 1) | (i & 1);      // 0..7
    const int nt2 = ((xcd >> 2) << 5) | (i >> 1);    // 0..63 (128-col panels)
    const int n0 = nt2 * 128;
    const int jb = mt * 64;

    const bhalf* gA = WcP + (size_t)mt * (NT * BLOB) + tid * 8;
    const bhalf* gB = XtP + (size_t)(nt2 >> 1) * (NT * BLOB)
                          + (nt2 & 1) * (BLOB / 2) + tid * 8;

    // wave tile 64x64: A rows wm*64.. (4 rb-blocks = 2048 bhalf), B rows wn*64
    const bhalf* pA0 = &As[0][wm * 2048 + soff];
    const bhalf* pA1 = &As[1][wm * 2048 + soff];
    const bhalf* pB0 = &Bs[0][wn * 2048 + soff];
    const bhalf* pB1 = &Bs[1][wn * 2048 + soff];

// 3 gload_lds per tile: A 16 KB (2 x 8KB), B 8 KB (1)
#define STAGE(t, bf) do {                                                     \
        const bhalf* sa_ = gA + (size_t)(t) * BLOB;                           \
        const bhalf* sb_ = gB + (size_t)(t) * BLOB;                           \
        GLDS(sa_,        &As[bf][tid * 8]);                                   \
        GLDS(sa_ + 4096, &As[bf][tid * 8 + 4096]);                            \
        GLDS(sb_,        &Bs[bf][tid * 8]);                                   \
    } while (0)

#define MF(mi, ni, A_, B_) acc[mi][ni] = \
    __builtin_amdgcn_mfma_f32_16x16x32_bf16(A_, B_, acc[mi][ni], 0, 0, 0)

// one K-32 tile from buffer q: 8 ds_read_b128 + 16 MFMA, compiler-scheduled
#define CT(q) do {                                                            \
    bf16x8 b0 = *(const bf16x8*)(pB##q);                                      \
    bf16x8 b1 = *(const bf16x8*)(pB##q + 512);                                \
    bf16x8 b2 = *(const bf16x8*)(pB##q + 1024);                               \
    bf16x8 b3 = *(const bf16x8*)(pB##q + 1536);                               \
    bf16x8 a0 = *(const bf16x8*)(pA##q);                                      \
    bf16x8 a1 = *(const bf16x8*)(pA##q + 512);                                \
    bf16x8 a2 = *(const bf16x8*)(pA##q + 1024);                               \
    bf16x8 a3 = *(const bf16x8*)(pA##q + 1536);                               \
    __builtin_amdgcn_s_setprio(1);                                            \
    MF(0,0,a0,b0); MF(0,1,a0,b1); MF(0,2,a0,b2); MF(0,3,a0,b3);               \
    MF(1,0,a1,b0); MF(1,1,a1,b1); MF(1,2,a1,b2); MF(1,3,a1,b3);               \
    MF(2,0,a2,b0); MF(2,1,a2,b1); MF(2,2,a2,b2); MF(2,3,a2,b3);               \
    MF(3,0,a3,b0); MF(3,1,a3,b1); MF(3,2,a3,b2); MF(3,3,a3,b3);               \
    __builtin_amdgcn_s_setprio(0);                                            \
} while (0)

    f32x4 acc[4][4] = {};

    // prologue
    STAGE(0, 0);

    // ---- z_hat finalize (hidden under prologue): mt==0, 128 cols/block ----
    if (mt == 0 && tid < 128) {
        const int n = n0 + tid;
        float s = 0.f;
        #pragma unroll
        for (int kt2 = 0; kt2 < NT; ++kt2) s += zpart[(size_t)kt2 * BB + n];
        const float v = (s + bias[2048] + 1.f) * 0.5f;
        out[(size_t)2 * HB + n] = fminf(fmaxf(v, 0.f), 1.f);
    }

    // steady state: at top of tile t only tile t's 3 loads are outstanding;
    // VM0 drains them (they had all of CT(t-1) to land); one barrier/tile;
    // STAGE(t+1) issues before CT(t) so it overlaps the compute.
    for (int t = 0; t < 46; t += 2) {
        VM0(); SBAR(); STAGE(t + 1, 1); CT(0);
        VM0(); SBAR(); STAGE(t + 2, 0); CT(1);
    }
    VM0(); SBAR(); STAGE(47, 1); CT(0);      // t=46
    VM0(); SBAR(); CT(1);                    // t=47

    // ---- fused gate epilogue: acc[mi][ni][r] = gate r of hidden j ----
    const int colbase = n0 + wn * 64 + lr;
    const int jloc0   = wm * 16 + hi;
    float zc[4], zbc[4];
    #pragma unroll
    for (int ni = 0; ni < 4; ++ni) {
        zc[ni]  = z[colbase + ni * 16];
        zbc[ni] = zb[colbase + ni * 16];
    }
    #pragma unroll
    for (int mi = 0; mi < 4; ++mi) {
        const int j = jb + jloc0 + mi * 4;           // hidden index
        const float bf_ = bias[j];
        const float bi_ = bias[512 + j];
        const float bo_ = bias[1024 + j];
        const float bg_ = bias[1536 + j];
        #pragma unroll
        for (int ni = 0; ni < 4; ++ni) {
            const int col = colbase + ni * 16;
            const size_t idx = (size_t)j * BB + col;
            const float cv = c_in[idx];
            const float hv = h_in[idx];
            const float fv = sigmf(acc[mi][ni][0] + bf_);
            const float iv = sigmf(acc[mi][ni][1] + bi_);
            const float ov = sigmf(acc[mi][ni][2] + bo_);
            const float gv = tanhfast(acc[mi][ni][3] + bg_);
            const float ig = iv * gv;
            const float zq = zc[ni], zbq = zbc[ni];
            const float cn = zq * ig + (1.f - zq) * (1.f - zbq) * cv
                           + (1.f - zq) * zbq * (fv * cv + ig);
            const float tc = tanhfast(cn);
            const float hn = (zq + (1.f - zq) * zbq) * ov * tc
                           + (1.f - zq) * (1.f - zbq) * hv;
            out[idx]      = hn;
            out[HB + idx] = cn;
        }
    }
}

// ---------------------------------------------------------------------------
extern "C" void kernel_launch(void* const* d_in, const int* in_sizes, int n_in,
                              void* d_out, int out_size, void* d_ws, size_t ws_size,
                              hipStream_t stream) {
    const float* c    = (const float*)d_in[0];
    const float* hb   = (const float*)d_in[1];
    const float* h    = (const float*)d_in[2];
    const float* ht   = (const float*)d_in[3];
    const float* z    = (const float*)d_in[4];
    const float* zb   = (const float*)d_in[5];
    const float* U11  = (const float*)d_in[6];
    const float* U21  = (const float*)d_in[7];
    const float* W01  = (const float*)d_in[8];
    const float* bias = (const float*)d_in[9];
    float* out = (float*)d_out;

    char* ws = (char*)d_ws;
    bhalf* XtP   = (bhalf*)ws;                     // 32*48*16KB = 25165824 B
    bhalf* WcP   = (bhalf*)(ws + 25165824);        //  8*48*16KB =  6291456 B
    float* zpart = (float*)(ws + 25165824 + 6291456);  // 48*8192*4 = 1572864 B

    prep_all  <<<2048, 256, 0, stream>>>(h, ht, hb, z, zb, U11, U21, W01,
                                         XtP, WcP, zpart);
    gemm_fused<<<512, 512, 0, stream>>>(WcP, XtP, bias, c, h, z, zb,
                                        zpart, out);
}